// Round 2
// baseline (220.518 us; speedup 1.0000x reference)
//
#include <hip/hip_runtime.h>
#include <hip/hip_bf16.h>
#include <stdint.h>

#define N_ROWS 512
#define D_DIM  512
#define C_CLS  100000

#define SCALE_F    64.0f
#define EPS_F      1e-7f
#define COS_M_F    0.8775825618903728f
#define SIN_M_F    0.4794255386042030f
#define THRESH_F  -0.8775825618903728f
#define MM_F       0.2397127693021015f

#define BM 128
#define BN 128
#define BK 32
#define NB 782          // ceil(100000/128)
#define MB 4            // 512/128

// ---- ws layout (bytes) ----
#define XN_OFF     0                          // bf16 bits [512][512]
#define XNORM_OFF  (512*512*2)                // f32 [512]
#define WNORM_OFF  (XNORM_OFF + 512*4)        // f32 [100096]
#define TL_OFF     (WNORM_OFF + 100096*4)     // f32 [512]
#define CTM_OFF    (TL_OFF + 512*4)           // f32 [512]
#define FTL_OFF    (CTM_OFF + 512*4)          // f32 [512]
#define TNEW_OFF   (FTL_OFF + 512*4)          // f32 [1] (padded)
#define PMAX_OFF   (TNEW_OFF + 256)           // f32 [512][NB]
#define PSUM_OFF   (PMAX_OFF + 512*NB*4)      // f32 [512][NB]
#define LOSSI_OFF  (PSUM_OFF + 512*NB*4)      // f32 [512]

typedef __attribute__((ext_vector_type(8))) short bf16x8;
typedef __attribute__((ext_vector_type(4))) float f32x4;

__device__ inline unsigned short f2bf(float f) {
    union { float f; unsigned int u; } a; a.f = f;
    unsigned int r = (a.u + 0x7FFFu + ((a.u >> 16) & 1u)) >> 16;
    return (unsigned short)r;
}

__device__ inline float wave_sum64(float v) {
    #pragma unroll
    for (int m = 1; m < 64; m <<= 1) v += __shfl_xor(v, m);
    return v;
}

// K1: x row norms + xn bf16.  grid 512 x 64
__global__ void k_xnorm(const float* __restrict__ x,
                        unsigned short* __restrict__ xn,
                        float* __restrict__ xnorm) {
    int row = blockIdx.x;
    int lane = threadIdx.x;
    const float* xr = x + row * D_DIM + lane * 8;
    float4 v0 = *(const float4*)(xr);
    float4 v1 = *(const float4*)(xr + 4);
    float s = v0.x*v0.x + v0.y*v0.y + v0.z*v0.z + v0.w*v0.w
            + v1.x*v1.x + v1.y*v1.y + v1.z*v1.z + v1.w*v1.w;
    s = wave_sum64(s);
    float nrm = sqrtf(s);
    if (lane == 0) xnorm[row] = nrm;
    float inv = 1.0f / nrm;
    union { unsigned short h[8]; uint4 q; } u;
    u.h[0]=f2bf(v0.x*inv); u.h[1]=f2bf(v0.y*inv); u.h[2]=f2bf(v0.z*inv); u.h[3]=f2bf(v0.w*inv);
    u.h[4]=f2bf(v1.x*inv); u.h[5]=f2bf(v1.y*inv); u.h[6]=f2bf(v1.z*inv); u.h[7]=f2bf(v1.w*inv);
    *(uint4*)(xn + row * D_DIM + lane * 8) = u.q;
}

// K2: weight row norms.  grid 25000 x 256 (wave per row)
__global__ void k_wnorm(const float* __restrict__ w, float* __restrict__ wnorm) {
    int row = blockIdx.x * 4 + (threadIdx.x >> 6);
    int lane = threadIdx.x & 63;
    const float* wr = w + (size_t)row * D_DIM + lane * 8;
    float4 v0 = *(const float4*)(wr);
    float4 v1 = *(const float4*)(wr + 4);
    float s = v0.x*v0.x + v0.y*v0.y + v0.z*v0.z + v0.w*v0.w
            + v1.x*v1.x + v1.y*v1.y + v1.z*v1.z + v1.w*v1.w;
    s = wave_sum64(s);
    if (lane == 0) wnorm[row] = sqrtf(s);
}

// K3: per-row target logit + margin terms.  grid 512 x 64
__global__ void k_tlogit(const float* __restrict__ x, const float* __restrict__ w,
                         const float* __restrict__ xnorm, const float* __restrict__ wnorm,
                         const int* __restrict__ target,
                         float* __restrict__ tl, float* __restrict__ ctm,
                         float* __restrict__ ftl) {
    int row = blockIdx.x;
    int lane = threadIdx.x;
    int tgt = target[row];
    const float* xr = x + row * D_DIM + lane * 8;
    const float* wr = w + (size_t)tgt * D_DIM + lane * 8;
    float4 a0 = *(const float4*)(xr),     a1 = *(const float4*)(xr + 4);
    float4 b0 = *(const float4*)(wr),     b1 = *(const float4*)(wr + 4);
    float s = a0.x*b0.x + a0.y*b0.y + a0.z*b0.z + a0.w*b0.w
            + a1.x*b1.x + a1.y*b1.y + a1.z*b1.z + a1.w*b1.w;
    s = wave_sum64(s);
    if (lane == 0) {
        float c = s / (xnorm[row] * wnorm[tgt]);
        c = fminf(fmaxf(c, -1.0f + EPS_F), 1.0f - EPS_F);
        float sn = sqrtf(fmaxf(1.0f - c * c, 0.0f));
        float cm = c * COS_M_F - sn * SIN_M_F;
        tl[row]  = c;
        ctm[row] = cm;
        ftl[row] = (c > THRESH_F) ? cm : (c - MM_F);
    }
}

// K3b: t_new = mean(tl)*0.01 + 0.99*t.  1 x 512
__global__ void k_tnew(const float* __restrict__ tl, const float* __restrict__ t,
                       float* __restrict__ tnew) {
    __shared__ float s[512];
    int tid = threadIdx.x;
    s[tid] = tl[tid];
    __syncthreads();
    for (int off = 256; off > 0; off >>= 1) {
        if (tid < off) s[tid] += s[tid + off];
        __syncthreads();
    }
    if (tid == 0) tnew[0] = (s[0] / 512.0f) * 0.01f + 0.99f * t[0];
}

// K4: GEMM (512 x 100000 x 512 bf16 MFMA) + CurricularFace epilogue + per-row
// per-nblock (max, sumexp) partials.  grid NB*MB x 256
__global__ __launch_bounds__(256) void k_gemm_epi(
        const unsigned short* __restrict__ xn,   // bf16 bits [512][512]
        const float* __restrict__ w,
        const float* __restrict__ wnorm,
        const int* __restrict__ target,
        const float* __restrict__ ctm,
        const float* __restrict__ ftl,
        const float* __restrict__ tnew,
        float* __restrict__ pmax, float* __restrict__ psum) {
    __shared__ unsigned short As[BM * BK];
    __shared__ unsigned short Bs[BN * BK];
    __shared__ int   tgt_s[BM];
    __shared__ float ctm_s[BM];
    __shared__ float ftl_s[BM];
    __shared__ float redM[2][BM];
    __shared__ float redS[2][BM];

    int bx = blockIdx.x;
    int nb = bx >> 2, mb = bx & 3;        // 4 consecutive blocks share B tile (L2)
    int rowbase = mb * BM, colbase = nb * BN;
    int tid = threadIdx.x;
    int lane = tid & 63, wid = tid >> 6;
    int wm = wid >> 1, wn = wid & 1;

    if (tid < BM) {
        int rg = rowbase + tid;
        tgt_s[tid] = target[rg];
        ctm_s[tid] = ctm[rg];
        ftl_s[tid] = ftl[rg];
    }
    float tn = tnew[0];

    // staging assignment: thread -> (row/col = tid>>1, k-quarter = (tid&1)*16)
    int srow = tid >> 1;
    int skq  = (tid & 1) * 16;
    int cg = colbase + srow;
    float wscale = 0.0f;
    if (cg < C_CLS) wscale = 1.0f / wnorm[cg];

    f32x4 acc[4][4];
    #pragma unroll
    for (int m = 0; m < 4; m++)
        #pragma unroll
        for (int n = 0; n < 4; n++)
            acc[m][n] = (f32x4){0.f, 0.f, 0.f, 0.f};

    for (int kt = 0; kt < D_DIM / BK; ++kt) {
        int k0 = kt * BK;
        __syncthreads();
        // stage A (already bf16)
        {
            const uint4* src = (const uint4*)(xn + (rowbase + srow) * D_DIM + k0 + skq);
            uint4 a0 = src[0], a1 = src[1];
            *(uint4*)(&As[srow * BK + skq])     = a0;
            *(uint4*)(&As[srow * BK + skq + 8]) = a1;
        }
        // stage B: f32 load, normalize, convert to bf16
        {
            union { unsigned short h[16]; uint4 q[2]; } pk;
            if (cg < C_CLS) {
                const float4* src = (const float4*)(w + (size_t)cg * D_DIM + k0 + skq);
                #pragma unroll
                for (int q = 0; q < 4; q++) {
                    float4 v = src[q];
                    pk.h[q*4+0] = f2bf(v.x * wscale);
                    pk.h[q*4+1] = f2bf(v.y * wscale);
                    pk.h[q*4+2] = f2bf(v.z * wscale);
                    pk.h[q*4+3] = f2bf(v.w * wscale);
                }
            } else {
                #pragma unroll
                for (int j = 0; j < 16; j++) pk.h[j] = 0;
            }
            *(uint4*)(&Bs[srow * BK + skq])     = pk.q[0];
            *(uint4*)(&Bs[srow * BK + skq + 8]) = pk.q[1];
        }
        __syncthreads();
        // fragments + MFMA
        int fr = lane & 15, kg = (lane >> 4) * 8;
        bf16x8 af[4], bfr[4];
        #pragma unroll
        for (int m = 0; m < 4; m++)
            af[m] = *(const bf16x8*)(&As[(wm * 64 + m * 16 + fr) * BK + kg]);
        #pragma unroll
        for (int n = 0; n < 4; n++)
            bfr[n] = *(const bf16x8*)(&Bs[(wn * 64 + n * 16 + fr) * BK + kg]);
        #pragma unroll
        for (int m = 0; m < 4; m++)
            #pragma unroll
            for (int n = 0; n < 4; n++)
                acc[m][n] = __builtin_amdgcn_mfma_f32_16x16x32_bf16(af[m], bfr[n], acc[m][n], 0, 0, 0);
    }

    // ---- fused CurricularFace epilogue + per-row online (max, sumexp) ----
    int cgrp = lane & 15, rgrp = lane >> 4;
    #pragma unroll
    for (int m = 0; m < 4; m++) {
        #pragma unroll
        for (int reg = 0; reg < 4; reg++) {
            int rl = wm * 64 + m * 16 + rgrp * 4 + reg;
            int tr = tgt_s[rl];
            float cm = ctm_s[rl];
            float vv[4];
            bool valid[4];
            #pragma unroll
            for (int n = 0; n < 4; n++) {
                int cl = wn * 64 + n * 16 + cgrp;
                int cgl = colbase + cl;
                float c = acc[m][n][reg];
                c = fminf(fmaxf(c, -1.0f + EPS_F), 1.0f - EPS_F);
                float v;
                if (cgl >= C_CLS)      { v = -3.0e38f; valid[n] = false; }
                else if (cgl == tr)    { v = ftl_s[rl] * SCALE_F; valid[n] = true; }
                else {
                    v = (c > cm) ? c * (tn + c) : c;
                    v *= SCALE_F;
                    valid[n] = true;
                }
                vv[n] = v;
            }
            float mx = fmaxf(fmaxf(vv[0], vv[1]), fmaxf(vv[2], vv[3]));
            #pragma unroll
            for (int msk = 1; msk < 16; msk <<= 1) mx = fmaxf(mx, __shfl_xor(mx, msk));
            float sm = 0.0f;
            #pragma unroll
            for (int n = 0; n < 4; n++) sm += valid[n] ? __expf(vv[n] - mx) : 0.0f;
            #pragma unroll
            for (int msk = 1; msk < 16; msk <<= 1) sm += __shfl_xor(sm, msk);
            if (cgrp == 0) { redM[wn][rl] = mx; redS[wn][rl] = sm; }
        }
    }
    __syncthreads();
    if (tid < BM) {
        float m0 = redM[0][tid], s0 = redS[0][tid];
        float m1 = redM[1][tid], s1 = redS[1][tid];
        float M = fmaxf(m0, m1);
        float S = s0 * __expf(m0 - M) + s1 * __expf(m1 - M);
        size_t idx = (size_t)(rowbase + tid) * NB + nb;
        pmax[idx] = M;
        psum[idx] = S;
    }
}

// K5: per-row logsumexp over NB partials -> loss_i.  grid 512 x 256
__global__ void k_rowlse(const float* __restrict__ pmax, const float* __restrict__ psum,
                         const float* __restrict__ ftl, float* __restrict__ lossi) {
    int row = blockIdx.x, tid = threadIdx.x;
    float M = -3.0e38f, S = 0.0f;
    for (int nb = tid; nb < NB; nb += 256) {
        float m = pmax[(size_t)row * NB + nb];
        float s = psum[(size_t)row * NB + nb];
        float nm = fmaxf(M, m);
        S = S * __expf(M - nm) + s * __expf(m - nm);
        M = nm;
    }
    __shared__ float sM[256], sS[256];
    sM[tid] = M; sS[tid] = S;
    __syncthreads();
    for (int off = 128; off > 0; off >>= 1) {
        if (tid < off) {
            float m2 = sM[tid + off], s2 = sS[tid + off];
            float nm = fmaxf(sM[tid], m2);
            sS[tid] = sS[tid] * __expf(sM[tid] - nm) + s2 * __expf(m2 - nm);
            sM[tid] = nm;
        }
        __syncthreads();
    }
    if (tid == 0) lossi[row] = logf(sS[0]) + sM[0] - SCALE_F * ftl[row];
}

// K6: loss = mean(loss_i).  1 x 512
__global__ void k_final(const float* __restrict__ lossi, float* __restrict__ out) {
    __shared__ float s[512];
    int tid = threadIdx.x;
    s[tid] = lossi[tid];
    __syncthreads();
    for (int off = 256; off > 0; off >>= 1) {
        if (tid < off) s[tid] += s[tid + off];
        __syncthreads();
    }
    if (tid == 0) out[0] = s[0] / 512.0f;
}

extern "C" void kernel_launch(void* const* d_in, const int* in_sizes, int n_in,
                              void* d_out, int out_size, void* d_ws, size_t ws_size,
                              hipStream_t stream) {
    const float* x      = (const float*)d_in[0];
    const float* w      = (const float*)d_in[1];
    const float* t      = (const float*)d_in[2];
    const int*   target = (const int*)d_in[3];

    char* ws = (char*)d_ws;
    unsigned short* xn  = (unsigned short*)(ws + XN_OFF);
    float* xnorm = (float*)(ws + XNORM_OFF);
    float* wnorm = (float*)(ws + WNORM_OFF);
    float* tl    = (float*)(ws + TL_OFF);
    float* ctm   = (float*)(ws + CTM_OFF);
    float* ftl   = (float*)(ws + FTL_OFF);
    float* tnew  = (float*)(ws + TNEW_OFF);
    float* pmax  = (float*)(ws + PMAX_OFF);
    float* psum  = (float*)(ws + PSUM_OFF);
    float* lossi = (float*)(ws + LOSSI_OFF);
    float* out   = (float*)d_out;

    k_xnorm<<<dim3(N_ROWS), dim3(64), 0, stream>>>(x, xn, xnorm);
    k_wnorm<<<dim3(C_CLS / 4), dim3(256), 0, stream>>>(w, wnorm);
    k_tlogit<<<dim3(N_ROWS), dim3(64), 0, stream>>>(x, w, xnorm, wnorm, target, tl, ctm, ftl);
    k_tnew<<<dim3(1), dim3(512), 0, stream>>>(tl, t, tnew);
    k_gemm_epi<<<dim3(NB * MB), dim3(256), 0, stream>>>(xn, w, wnorm, target, ctm, ftl, tnew, pmax, psum);
    k_rowlse<<<dim3(N_ROWS), dim3(256), 0, stream>>>(pmax, psum, ftl, lossi);
    k_final<<<dim3(1), dim3(512), 0, stream>>>(lossi, out);
}

// Round 3
// 216.950 us; speedup vs baseline: 1.0164x; 1.0164x over previous
//
#include <hip/hip_runtime.h>
#include <hip/hip_bf16.h>
#include <stdint.h>

#define N_ROWS 512
#define D_DIM  512
#define C_CLS  100000
#define C_PAD  100096           // 782*128

#define SCALE_F    64.0f
#define EPS_F      1e-7f
#define COS_M_F    0.8775825618903728f
#define SIN_M_F    0.4794255386042030f
#define THRESH_F  -0.8775825618903728f
#define MM_F       0.2397127693021015f

#define NB 782          // ceil(100000/128)
#define NWG (NB*4)      // 3128 = 8*391
#define WGS_PER_XCD 391

// ---- ws layout (bytes) ----
#define XN_OFF     0                          // bf16 bits [512][512]
#define XNORM_OFF  (XN_OFF + 512*512*2)       // f32 [512]
#define WNORM_OFF  (XNORM_OFF + 2048)         // f32 [100096]
#define TL_OFF     (WNORM_OFF + 100096*4)     // f32 [512]
#define CTM_OFF    (TL_OFF + 2048)            // f32 [512]
#define FTL_OFF    (CTM_OFF + 2048)           // f32 [512]
#define TNEW_OFF   (FTL_OFF + 2048)           // f32 [1] (padded)
#define PMAX_OFF   (TNEW_OFF + 256)           // f32 [512][NB]
#define PSUM_OFF   (PMAX_OFF + 512*NB*4)      // f32 [512][NB]
#define LOSSI_OFF  (PSUM_OFF + 512*NB*4)      // f32 [512]
#define WNBF_OFF   (LOSSI_OFF + 2048)         // bf16 bits [100096][512] (fast path only)
#define WS_NEED_FAST ((size_t)WNBF_OFF + (size_t)C_PAD*512*2)

typedef __attribute__((ext_vector_type(8))) short bf16x8;
typedef __attribute__((ext_vector_type(4))) float f32x4;

#define GLOAD_LDS16(gp, lp) \
    __builtin_amdgcn_global_load_lds((const __attribute__((address_space(1))) void*)(gp), \
                                     (__attribute__((address_space(3))) void*)(lp), 16, 0, 0)

__device__ inline unsigned short f2bf(float f) {
    union { float f; unsigned int u; } a; a.f = f;
    unsigned int r = (a.u + 0x7FFFu + ((a.u >> 16) & 1u)) >> 16;
    return (unsigned short)r;
}

__device__ inline float wave_sum64(float v) {
    #pragma unroll
    for (int m = 1; m < 64; m <<= 1) v += __shfl_xor(v, m);
    return v;
}

// K1: x row norms + xn bf16.  grid 512 x 64
__global__ void k_xnorm(const float* __restrict__ x,
                        unsigned short* __restrict__ xn,
                        float* __restrict__ xnorm) {
    int row = blockIdx.x;
    int lane = threadIdx.x;
    const float* xr = x + row * D_DIM + lane * 8;
    float4 v0 = *(const float4*)(xr);
    float4 v1 = *(const float4*)(xr + 4);
    float s = v0.x*v0.x + v0.y*v0.y + v0.z*v0.z + v0.w*v0.w
            + v1.x*v1.x + v1.y*v1.y + v1.z*v1.z + v1.w*v1.w;
    s = wave_sum64(s);
    float nrm = sqrtf(s);
    if (lane == 0) xnorm[row] = nrm;
    float inv = 1.0f / nrm;
    union { unsigned short h[8]; uint4 q; } u;
    u.h[0]=f2bf(v0.x*inv); u.h[1]=f2bf(v0.y*inv); u.h[2]=f2bf(v0.z*inv); u.h[3]=f2bf(v0.w*inv);
    u.h[4]=f2bf(v1.x*inv); u.h[5]=f2bf(v1.y*inv); u.h[6]=f2bf(v1.z*inv); u.h[7]=f2bf(v1.w*inv);
    *(uint4*)(xn + row * D_DIM + lane * 8) = u.q;
}

// K2 (fast): weight row norms + normalized bf16 W (pad rows zeroed).
// grid 25024 x 256 (wave per row)
__global__ void k_wnorm_bf16(const float* __restrict__ w, float* __restrict__ wnorm,
                             unsigned short* __restrict__ wnb) {
    int row = blockIdx.x * 4 + (threadIdx.x >> 6);
    int lane = threadIdx.x & 63;
    if (row < C_CLS) {
        const float* wr = w + (size_t)row * D_DIM + lane * 8;
        float4 v0 = *(const float4*)(wr);
        float4 v1 = *(const float4*)(wr + 4);
        float s = v0.x*v0.x + v0.y*v0.y + v0.z*v0.z + v0.w*v0.w
                + v1.x*v1.x + v1.y*v1.y + v1.z*v1.z + v1.w*v1.w;
        s = wave_sum64(s);
        float nrm = sqrtf(s);
        if (lane == 0) wnorm[row] = nrm;
        float inv = 1.0f / nrm;
        union { unsigned short h[8]; uint4 q; } u;
        u.h[0]=f2bf(v0.x*inv); u.h[1]=f2bf(v0.y*inv); u.h[2]=f2bf(v0.z*inv); u.h[3]=f2bf(v0.w*inv);
        u.h[4]=f2bf(v1.x*inv); u.h[5]=f2bf(v1.y*inv); u.h[6]=f2bf(v1.z*inv); u.h[7]=f2bf(v1.w*inv);
        *(uint4*)(wnb + (size_t)row * D_DIM + lane * 8) = u.q;
    } else {
        uint4 z = {0u, 0u, 0u, 0u};
        *(uint4*)(wnb + (size_t)row * D_DIM + lane * 8) = z;
    }
}

// K2 (fallback): weight row norms only.  grid 25000 x 256
__global__ void k_wnorm(const float* __restrict__ w, float* __restrict__ wnorm) {
    int row = blockIdx.x * 4 + (threadIdx.x >> 6);
    int lane = threadIdx.x & 63;
    const float* wr = w + (size_t)row * D_DIM + lane * 8;
    float4 v0 = *(const float4*)(wr);
    float4 v1 = *(const float4*)(wr + 4);
    float s = v0.x*v0.x + v0.y*v0.y + v0.z*v0.z + v0.w*v0.w
            + v1.x*v1.x + v1.y*v1.y + v1.z*v1.z + v1.w*v1.w;
    s = wave_sum64(s);
    if (lane == 0) wnorm[row] = sqrtf(s);
}

// K3: per-row target logit + margin terms (exact f32).  grid 512 x 64
__global__ void k_tlogit(const float* __restrict__ x, const float* __restrict__ w,
                         const float* __restrict__ xnorm, const float* __restrict__ wnorm,
                         const int* __restrict__ target,
                         float* __restrict__ tl, float* __restrict__ ctm,
                         float* __restrict__ ftl) {
    int row = blockIdx.x;
    int lane = threadIdx.x;
    int tgt = target[row];
    const float* xr = x + row * D_DIM + lane * 8;
    const float* wr = w + (size_t)tgt * D_DIM + lane * 8;
    float4 a0 = *(const float4*)(xr),     a1 = *(const float4*)(xr + 4);
    float4 b0 = *(const float4*)(wr),     b1 = *(const float4*)(wr + 4);
    float s = a0.x*b0.x + a0.y*b0.y + a0.z*b0.z + a0.w*b0.w
            + a1.x*b1.x + a1.y*b1.y + a1.z*b1.z + a1.w*b1.w;
    s = wave_sum64(s);
    if (lane == 0) {
        float c = s / (xnorm[row] * wnorm[tgt]);
        c = fminf(fmaxf(c, -1.0f + EPS_F), 1.0f - EPS_F);
        float sn = sqrtf(fmaxf(1.0f - c * c, 0.0f));
        float cm = c * COS_M_F - sn * SIN_M_F;
        tl[row]  = c;
        ctm[row] = cm;
        ftl[row] = (c > THRESH_F) ? cm : (c - MM_F);
    }
}

// K3b: t_new = mean(tl)*0.01 + 0.99*t.  1 x 512
__global__ void k_tnew(const float* __restrict__ tl, const float* __restrict__ t,
                       float* __restrict__ tnew) {
    __shared__ float s[512];
    int tid = threadIdx.x;
    s[tid] = tl[tid];
    __syncthreads();
    for (int off = 256; off > 0; off >>= 1) {
        if (tid < off) s[tid] += s[tid + off];
        __syncthreads();
    }
    if (tid == 0) tnew[0] = (s[0] / 512.0f) * 0.01f + 0.99f * t[0];
}

// ---------------------------------------------------------------------------
// K4 fast: pure-bf16 GEMM, 128x128 tile, BK=64, global_load_lds staging,
// bijective XCD swizzle (nb-major: 4 row-blocks of one col-block share an XCD)
// + fused CurricularFace epilogue + per-(row, nb) online (max,sumexp).
// grid 3128 x 256
// ---------------------------------------------------------------------------
__global__ __launch_bounds__(256) void k_gemm_fast(
        const unsigned short* __restrict__ xn,    // bf16 [512][512]
        const unsigned short* __restrict__ wnb,   // bf16 [100096][512], normalized
        const int* __restrict__ target,
        const float* __restrict__ ctm,
        const float* __restrict__ ftl,
        const float* __restrict__ tnew,
        float* __restrict__ pmax, float* __restrict__ psum) {
    __shared__ unsigned short As[128 * 64];
    __shared__ unsigned short Bs[128 * 64];
    __shared__ int   tgt_s[128];
    __shared__ float ctm_s[128];
    __shared__ float ftl_s[128];
    __shared__ float redM[2][128];
    __shared__ float redS[2][128];

    // bijective XCD remap: hw round-robins blockIdx%8 across XCDs; give each
    // XCD a contiguous logical chunk so mb-siblings (logical 4n..4n+3) share L2.
    int bx = blockIdx.x;
    int logical = (bx & 7) * WGS_PER_XCD + (bx >> 3);
    int nb = logical >> 2, mb = logical & 3;
    int rowbase = mb * 128, colbase = nb * 128;
    int tid = threadIdx.x;
    int lane = tid & 63, wid = tid >> 6;
    int wm = wid >> 1, wn = wid & 1;

    if (tid < 128) {
        int rg = rowbase + tid;
        tgt_s[tid] = target[rg];
        ctm_s[tid] = ctm[rg];
        ftl_s[tid] = ftl[rg];
    }
    float tn = tnew[0];

    f32x4 acc[4][4];
    #pragma unroll
    for (int m = 0; m < 4; m++)
        #pragma unroll
        for (int n = 0; n < 4; n++)
            acc[m][n] = (f32x4){0.f, 0.f, 0.f, 0.f};

    const char* Ab = (const char*)xn;     // row stride 1024 B
    const char* Bb = (const char*)wnb;    // row stride 1024 B

    for (int kt = 0; kt < D_DIM / 64; ++kt) {
        __syncthreads();
        // stage 16 KB each of A and B via global_load_lds width-16.
        // LDS layout: tile[row][k], 128 B per row; wave wid owns bytes
        // [wid*4096, wid*4096+4096) in 4 calls of 1 KB (64 lanes x 16 B).
        #pragma unroll
        for (int c = 0; c < 4; ++c) {
            int lo = wid * 4096 + c * 1024;          // wave-uniform LDS base
            int o  = lo + lane * 16;                  // this lane's byte
            int row = o >> 7, kb = o & 127;
            GLOAD_LDS16(Ab + (size_t)(rowbase + row) * 1024 + kt * 128 + kb,
                        (char*)As + lo);
            GLOAD_LDS16(Bb + (size_t)(colbase + row) * 1024 + kt * 128 + kb,
                        (char*)Bs + lo);
        }
        __syncthreads();

        int fr = lane & 15;
        int kg2 = (lane >> 4) * 16;                   // k-group byte offset
        #pragma unroll
        for (int kk = 0; kk < 2; ++kk) {
            bf16x8 af[4], bfr[4];
            #pragma unroll
            for (int m = 0; m < 4; m++)
                af[m] = *(const bf16x8*)((const char*)As + (wm*64 + m*16 + fr)*128 + kk*64 + kg2);
            #pragma unroll
            for (int n = 0; n < 4; n++)
                bfr[n] = *(const bf16x8*)((const char*)Bs + (wn*64 + n*16 + fr)*128 + kk*64 + kg2);
            #pragma unroll
            for (int m = 0; m < 4; m++)
                #pragma unroll
                for (int n = 0; n < 4; n++)
                    acc[m][n] = __builtin_amdgcn_mfma_f32_16x16x32_bf16(af[m], bfr[n], acc[m][n], 0, 0, 0);
        }
    }

    // ---- fused CurricularFace epilogue + per-row online (max, sumexp) ----
    int cgrp = lane & 15, rgrp = lane >> 4;
    #pragma unroll
    for (int m = 0; m < 4; m++) {
        #pragma unroll
        for (int reg = 0; reg < 4; reg++) {
            int rl = wm * 64 + m * 16 + rgrp * 4 + reg;
            int tr = tgt_s[rl];
            float cm = ctm_s[rl];
            float vv[4];
            bool valid[4];
            #pragma unroll
            for (int n = 0; n < 4; n++) {
                int cl = wn * 64 + n * 16 + cgrp;
                int cgl = colbase + cl;
                float c = acc[m][n][reg];
                c = fminf(fmaxf(c, -1.0f + EPS_F), 1.0f - EPS_F);
                float v;
                if (cgl >= C_CLS)      { v = -3.0e38f; valid[n] = false; }
                else if (cgl == tr)    { v = ftl_s[rl] * SCALE_F; valid[n] = true; }
                else {
                    v = (c > cm) ? c * (tn + c) : c;
                    v *= SCALE_F;
                    valid[n] = true;
                }
                vv[n] = v;
            }
            float mx = fmaxf(fmaxf(vv[0], vv[1]), fmaxf(vv[2], vv[3]));
            #pragma unroll
            for (int msk = 1; msk < 16; msk <<= 1) mx = fmaxf(mx, __shfl_xor(mx, msk));
            float sm = 0.0f;
            #pragma unroll
            for (int n = 0; n < 4; n++) sm += valid[n] ? __expf(vv[n] - mx) : 0.0f;
            #pragma unroll
            for (int msk = 1; msk < 16; msk <<= 1) sm += __shfl_xor(sm, msk);
            if (cgrp == 0) { redM[wn][rl] = mx; redS[wn][rl] = sm; }
        }
    }
    __syncthreads();
    if (tid < 128) {
        float m0 = redM[0][tid], s0 = redS[0][tid];
        float m1 = redM[1][tid], s1 = redS[1][tid];
        float M = fmaxf(m0, m1);
        float S = s0 * __expf(m0 - M) + s1 * __expf(m1 - M);
        size_t idx = (size_t)(rowbase + tid) * NB + nb;
        pmax[idx] = M;
        psum[idx] = S;
    }
}

// ---------------------------------------------------------------------------
// K4 fallback (round-2 version): f32 W load + on-the-fly normalize/convert.
// grid NB*4 x 256
// ---------------------------------------------------------------------------
__global__ __launch_bounds__(256) void k_gemm_epi(
        const unsigned short* __restrict__ xn,
        const float* __restrict__ w,
        const float* __restrict__ wnorm,
        const int* __restrict__ target,
        const float* __restrict__ ctm,
        const float* __restrict__ ftl,
        const float* __restrict__ tnew,
        float* __restrict__ pmax, float* __restrict__ psum) {
    __shared__ unsigned short As[128 * 32];
    __shared__ unsigned short Bs[128 * 32];
    __shared__ int   tgt_s[128];
    __shared__ float ctm_s[128];
    __shared__ float ftl_s[128];
    __shared__ float redM[2][128];
    __shared__ float redS[2][128];

    int bx = blockIdx.x;
    int nb = bx >> 2, mb = bx & 3;
    int rowbase = mb * 128, colbase = nb * 128;
    int tid = threadIdx.x;
    int lane = tid & 63, wid = tid >> 6;
    int wm = wid >> 1, wn = wid & 1;

    if (tid < 128) {
        int rg = rowbase + tid;
        tgt_s[tid] = target[rg];
        ctm_s[tid] = ctm[rg];
        ftl_s[tid] = ftl[rg];
    }
    float tn = tnew[0];

    int srow = tid >> 1;
    int skq  = (tid & 1) * 16;
    int cg = colbase + srow;
    float wscale = 0.0f;
    if (cg < C_CLS) wscale = 1.0f / wnorm[cg];

    f32x4 acc[4][4];
    #pragma unroll
    for (int m = 0; m < 4; m++)
        #pragma unroll
        for (int n = 0; n < 4; n++)
            acc[m][n] = (f32x4){0.f, 0.f, 0.f, 0.f};

    for (int kt = 0; kt < D_DIM / 32; ++kt) {
        int k0 = kt * 32;
        __syncthreads();
        {
            const uint4* src = (const uint4*)(xn + (rowbase + srow) * D_DIM + k0 + skq);
            uint4 a0 = src[0], a1 = src[1];
            *(uint4*)(&As[srow * 32 + skq])     = a0;
            *(uint4*)(&As[srow * 32 + skq + 8]) = a1;
        }
        {
            union { unsigned short h[16]; uint4 q[2]; } pk;
            if (cg < C_CLS) {
                const float4* src = (const float4*)(w + (size_t)cg * D_DIM + k0 + skq);
                #pragma unroll
                for (int q = 0; q < 4; q++) {
                    float4 v = src[q];
                    pk.h[q*4+0] = f2bf(v.x * wscale);
                    pk.h[q*4+1] = f2bf(v.y * wscale);
                    pk.h[q*4+2] = f2bf(v.z * wscale);
                    pk.h[q*4+3] = f2bf(v.w * wscale);
                }
            } else {
                #pragma unroll
                for (int j = 0; j < 16; j++) pk.h[j] = 0;
            }
            *(uint4*)(&Bs[srow * 32 + skq])     = pk.q[0];
            *(uint4*)(&Bs[srow * 32 + skq + 8]) = pk.q[1];
        }
        __syncthreads();
        int fr = lane & 15, kg = (lane >> 4) * 8;
        bf16x8 af[4], bfr[4];
        #pragma unroll
        for (int m = 0; m < 4; m++)
            af[m] = *(const bf16x8*)(&As[(wm * 64 + m * 16 + fr) * 32 + kg]);
        #pragma unroll
        for (int n = 0; n < 4; n++)
            bfr[n] = *(const bf16x8*)(&Bs[(wn * 64 + n * 16 + fr) * 32 + kg]);
        #pragma unroll
        for (int m = 0; m < 4; m++)
            #pragma unroll
            for (int n = 0; n < 4; n++)
                acc[m][n] = __builtin_amdgcn_mfma_f32_16x16x32_bf16(af[m], bfr[n], acc[m][n], 0, 0, 0);
    }

    int cgrp = lane & 15, rgrp = lane >> 4;
    #pragma unroll
    for (int m = 0; m < 4; m++) {
        #pragma unroll
        for (int reg = 0; reg < 4; reg++) {
            int rl = wm * 64 + m * 16 + rgrp * 4 + reg;
            int tr = tgt_s[rl];
            float cm = ctm_s[rl];
            float vv[4];
            bool valid[4];
            #pragma unroll
            for (int n = 0; n < 4; n++) {
                int cl = wn * 64 + n * 16 + cgrp;
                int cgl = colbase + cl;
                float c = acc[m][n][reg];
                c = fminf(fmaxf(c, -1.0f + EPS_F), 1.0f - EPS_F);
                float v;
                if (cgl >= C_CLS)      { v = -3.0e38f; valid[n] = false; }
                else if (cgl == tr)    { v = ftl_s[rl] * SCALE_F; valid[n] = true; }
                else {
                    v = (c > cm) ? c * (tn + c) : c;
                    v *= SCALE_F;
                    valid[n] = true;
                }
                vv[n] = v;
            }
            float mx = fmaxf(fmaxf(vv[0], vv[1]), fmaxf(vv[2], vv[3]));
            #pragma unroll
            for (int msk = 1; msk < 16; msk <<= 1) mx = fmaxf(mx, __shfl_xor(mx, msk));
            float sm = 0.0f;
            #pragma unroll
            for (int n = 0; n < 4; n++) sm += valid[n] ? __expf(vv[n] - mx) : 0.0f;
            #pragma unroll
            for (int msk = 1; msk < 16; msk <<= 1) sm += __shfl_xor(sm, msk);
            if (cgrp == 0) { redM[wn][rl] = mx; redS[wn][rl] = sm; }
        }
    }
    __syncthreads();
    if (tid < 128) {
        float m0 = redM[0][tid], s0 = redS[0][tid];
        float m1 = redM[1][tid], s1 = redS[1][tid];
        float M = fmaxf(m0, m1);
        float S = s0 * __expf(m0 - M) + s1 * __expf(m1 - M);
        size_t idx = (size_t)(rowbase + tid) * NB + nb;
        pmax[idx] = M;
        psum[idx] = S;
    }
}

// K5: per-row logsumexp over NB partials -> loss_i.  grid 512 x 256
__global__ void k_rowlse(const float* __restrict__ pmax, const float* __restrict__ psum,
                         const float* __restrict__ ftl, float* __restrict__ lossi) {
    int row = blockIdx.x, tid = threadIdx.x;
    float M = -3.0e38f, S = 0.0f;
    for (int nb = tid; nb < NB; nb += 256) {
        float m = pmax[(size_t)row * NB + nb];
        float s = psum[(size_t)row * NB + nb];
        float nm = fmaxf(M, m);
        S = S * __expf(M - nm) + s * __expf(m - nm);
        M = nm;
    }
    __shared__ float sM[256], sS[256];
    sM[tid] = M; sS[tid] = S;
    __syncthreads();
    for (int off = 128; off > 0; off >>= 1) {
        if (tid < off) {
            float m2 = sM[tid + off], s2 = sS[tid + off];
            float nm = fmaxf(sM[tid], m2);
            sS[tid] = sS[tid] * __expf(sM[tid] - nm) + s2 * __expf(m2 - nm);
            sM[tid] = nm;
        }
        __syncthreads();
    }
    if (tid == 0) lossi[row] = logf(sS[0]) + sM[0] - SCALE_F * ftl[row];
}

// K6: loss = mean(loss_i).  1 x 512
__global__ void k_final(const float* __restrict__ lossi, float* __restrict__ out) {
    __shared__ float s[512];
    int tid = threadIdx.x;
    s[tid] = lossi[tid];
    __syncthreads();
    for (int off = 256; off > 0; off >>= 1) {
        if (tid < off) s[tid] += s[tid + off];
        __syncthreads();
    }
    if (tid == 0) out[0] = s[0] / 512.0f;
}

extern "C" void kernel_launch(void* const* d_in, const int* in_sizes, int n_in,
                              void* d_out, int out_size, void* d_ws, size_t ws_size,
                              hipStream_t stream) {
    const float* x      = (const float*)d_in[0];
    const float* w      = (const float*)d_in[1];
    const float* t      = (const float*)d_in[2];
    const int*   target = (const int*)d_in[3];

    char* ws = (char*)d_ws;
    unsigned short* xn  = (unsigned short*)(ws + XN_OFF);
    float* xnorm = (float*)(ws + XNORM_OFF);
    float* wnorm = (float*)(ws + WNORM_OFF);
    float* tl    = (float*)(ws + TL_OFF);
    float* ctm   = (float*)(ws + CTM_OFF);
    float* ftl   = (float*)(ws + FTL_OFF);
    float* tnew  = (float*)(ws + TNEW_OFF);
    float* pmax  = (float*)(ws + PMAX_OFF);
    float* psum  = (float*)(ws + PSUM_OFF);
    float* lossi = (float*)(ws + LOSSI_OFF);
    unsigned short* wnb = (unsigned short*)(ws + WNBF_OFF);
    float* out   = (float*)d_out;

    bool fast = (ws_size >= WS_NEED_FAST);

    k_xnorm<<<dim3(N_ROWS), dim3(64), 0, stream>>>(x, xn, xnorm);
    if (fast) {
        k_wnorm_bf16<<<dim3(C_PAD / 4), dim3(256), 0, stream>>>(w, wnorm, wnb);
    } else {
        k_wnorm<<<dim3(C_CLS / 4), dim3(256), 0, stream>>>(w, wnorm);
    }
    k_tlogit<<<dim3(N_ROWS), dim3(64), 0, stream>>>(x, w, xnorm, wnorm, target, tl, ctm, ftl);
    k_tnew<<<dim3(1), dim3(512), 0, stream>>>(tl, t, tnew);
    if (fast) {
        k_gemm_fast<<<dim3(NWG), dim3(256), 0, stream>>>(xn, wnb, target, ctm, ftl, tnew, pmax, psum);
    } else {
        k_gemm_epi<<<dim3(NWG), dim3(256), 0, stream>>>(xn, w, wnorm, target, ctm, ftl, tnew, pmax, psum);
    }
    k_rowlse<<<dim3(N_ROWS), dim3(256), 0, stream>>>(pmax, psum, ftl, lossi);
    k_final<<<dim3(1), dim3(512), 0, stream>>>(lossi, out);
}

// Round 4
// 201.017 us; speedup vs baseline: 1.0970x; 1.0793x over previous
//
#include <hip/hip_runtime.h>
#include <hip/hip_bf16.h>
#include <stdint.h>

#define N_ROWS 512
#define D_DIM  512
#define C_CLS  100000
#define C_PAD  100096           // 782*128

#define SCALE_F    64.0f
#define EPS_F      1e-7f
#define COS_M_F    0.8775825618903728f
#define SIN_M_F    0.4794255386042030f
#define THRESH_F  -0.8775825618903728f
#define MM_F       0.2397127693021015f

#define NB 782          // ceil(100000/128)
#define NWG (NB*4)      // 3128 = 8*391
#define WGS_PER_XCD 391

// ---- ws layout (bytes) ----
#define XN_OFF     0                          // bf16 bits [512][512]
#define XNORM_OFF  (XN_OFF + 512*512*2)       // f32 [512]
#define WNORM_OFF  (XNORM_OFF + 2048)         // f32 [100096]
#define TL_OFF     (WNORM_OFF + 100096*4)     // f32 [512]
#define CTM_OFF    (TL_OFF + 2048)            // f32 [512]
#define FTL_OFF    (CTM_OFF + 2048)           // f32 [512]
#define TNEW_OFF   (FTL_OFF + 2048)           // f32 [1] (padded)
#define PMAX_OFF   (TNEW_OFF + 256)           // f32 [512][NB]
#define PSUM_OFF   (PMAX_OFF + 512*NB*4)      // f32 [512][NB]
#define LOSSI_OFF  (PSUM_OFF + 512*NB*4)      // f32 [512]
#define WNBF_OFF   (LOSSI_OFF + 2048)         // bf16 bits [100096][512] (fast path only)
#define WS_NEED_FAST ((size_t)WNBF_OFF + (size_t)C_PAD*512*2)

typedef __attribute__((ext_vector_type(8))) short bf16x8;
typedef __attribute__((ext_vector_type(4))) float f32x4;

#define GLOAD_LDS16(gp, lp) \
    __builtin_amdgcn_global_load_lds((const __attribute__((address_space(1))) void*)(gp), \
                                     (__attribute__((address_space(3))) void*)(lp), 16, 0, 0)

__device__ inline unsigned short f2bf(float f) {
    union { float f; unsigned int u; } a; a.f = f;
    unsigned int r = (a.u + 0x7FFFu + ((a.u >> 16) & 1u)) >> 16;
    return (unsigned short)r;
}

__device__ inline float wave_sum64(float v) {
    #pragma unroll
    for (int m = 1; m < 64; m <<= 1) v += __shfl_xor(v, m);
    return v;
}

// K1: x row norms + xn bf16.  grid 512 x 64
__global__ void k_xnorm(const float* __restrict__ x,
                        unsigned short* __restrict__ xn,
                        float* __restrict__ xnorm) {
    int row = blockIdx.x;
    int lane = threadIdx.x;
    const float* xr = x + row * D_DIM + lane * 8;
    float4 v0 = *(const float4*)(xr);
    float4 v1 = *(const float4*)(xr + 4);
    float s = v0.x*v0.x + v0.y*v0.y + v0.z*v0.z + v0.w*v0.w
            + v1.x*v1.x + v1.y*v1.y + v1.z*v1.z + v1.w*v1.w;
    s = wave_sum64(s);
    float nrm = sqrtf(s);
    if (lane == 0) xnorm[row] = nrm;
    float inv = 1.0f / nrm;
    union { unsigned short h[8]; uint4 q; } u;
    u.h[0]=f2bf(v0.x*inv); u.h[1]=f2bf(v0.y*inv); u.h[2]=f2bf(v0.z*inv); u.h[3]=f2bf(v0.w*inv);
    u.h[4]=f2bf(v1.x*inv); u.h[5]=f2bf(v1.y*inv); u.h[6]=f2bf(v1.z*inv); u.h[7]=f2bf(v1.w*inv);
    *(uint4*)(xn + row * D_DIM + lane * 8) = u.q;
}

// K2 (fast): weight row norms + normalized bf16 W (pad rows zeroed).
// grid 25024 x 256 (wave per row)
__global__ void k_wnorm_bf16(const float* __restrict__ w, float* __restrict__ wnorm,
                             unsigned short* __restrict__ wnb) {
    int row = blockIdx.x * 4 + (threadIdx.x >> 6);
    int lane = threadIdx.x & 63;
    if (row < C_CLS) {
        const float* wr = w + (size_t)row * D_DIM + lane * 8;
        float4 v0 = *(const float4*)(wr);
        float4 v1 = *(const float4*)(wr + 4);
        float s = v0.x*v0.x + v0.y*v0.y + v0.z*v0.z + v0.w*v0.w
                + v1.x*v1.x + v1.y*v1.y + v1.z*v1.z + v1.w*v1.w;
        s = wave_sum64(s);
        float nrm = sqrtf(s);
        if (lane == 0) wnorm[row] = nrm;
        float inv = 1.0f / nrm;
        union { unsigned short h[8]; uint4 q; } u;
        u.h[0]=f2bf(v0.x*inv); u.h[1]=f2bf(v0.y*inv); u.h[2]=f2bf(v0.z*inv); u.h[3]=f2bf(v0.w*inv);
        u.h[4]=f2bf(v1.x*inv); u.h[5]=f2bf(v1.y*inv); u.h[6]=f2bf(v1.z*inv); u.h[7]=f2bf(v1.w*inv);
        *(uint4*)(wnb + (size_t)row * D_DIM + lane * 8) = u.q;
    } else {
        uint4 z = {0u, 0u, 0u, 0u};
        *(uint4*)(wnb + (size_t)row * D_DIM + lane * 8) = z;
    }
}

// K2 (fallback): weight row norms only.  grid 25000 x 256
__global__ void k_wnorm(const float* __restrict__ w, float* __restrict__ wnorm) {
    int row = blockIdx.x * 4 + (threadIdx.x >> 6);
    int lane = threadIdx.x & 63;
    const float* wr = w + (size_t)row * D_DIM + lane * 8;
    float4 v0 = *(const float4*)(wr);
    float4 v1 = *(const float4*)(wr + 4);
    float s = v0.x*v0.x + v0.y*v0.y + v0.z*v0.z + v0.w*v0.w
            + v1.x*v1.x + v1.y*v1.y + v1.z*v1.z + v1.w*v1.w;
    s = wave_sum64(s);
    if (lane == 0) wnorm[row] = sqrtf(s);
}

// K3: per-row target logit + margin terms (exact f32).  grid 512 x 64
__global__ void k_tlogit(const float* __restrict__ x, const float* __restrict__ w,
                         const float* __restrict__ xnorm, const float* __restrict__ wnorm,
                         const int* __restrict__ target,
                         float* __restrict__ tl, float* __restrict__ ctm,
                         float* __restrict__ ftl) {
    int row = blockIdx.x;
    int lane = threadIdx.x;
    int tgt = target[row];
    const float* xr = x + row * D_DIM + lane * 8;
    const float* wr = w + (size_t)tgt * D_DIM + lane * 8;
    float4 a0 = *(const float4*)(xr),     a1 = *(const float4*)(xr + 4);
    float4 b0 = *(const float4*)(wr),     b1 = *(const float4*)(wr + 4);
    float s = a0.x*b0.x + a0.y*b0.y + a0.z*b0.z + a0.w*b0.w
            + a1.x*b1.x + a1.y*b1.y + a1.z*b1.z + a1.w*b1.w;
    s = wave_sum64(s);
    if (lane == 0) {
        float c = s / (xnorm[row] * wnorm[tgt]);
        c = fminf(fmaxf(c, -1.0f + EPS_F), 1.0f - EPS_F);
        float sn = sqrtf(fmaxf(1.0f - c * c, 0.0f));
        float cm = c * COS_M_F - sn * SIN_M_F;
        tl[row]  = c;
        ctm[row] = cm;
        ftl[row] = (c > THRESH_F) ? cm : (c - MM_F);
    }
}

// K3b: t_new = mean(tl)*0.01 + 0.99*t.  1 x 512
__global__ void k_tnew(const float* __restrict__ tl, const float* __restrict__ t,
                       float* __restrict__ tnew) {
    __shared__ float s[512];
    int tid = threadIdx.x;
    s[tid] = tl[tid];
    __syncthreads();
    for (int off = 256; off > 0; off >>= 1) {
        if (tid < off) s[tid] += s[tid + off];
        __syncthreads();
    }
    if (tid == 0) tnew[0] = (s[0] / 512.0f) * 0.01f + 0.99f * t[0];
}

// ---------------------------------------------------------------------------
// K4 fast: pure-bf16 GEMM, 128x128 tile, BK=64, double-buffered LDS with
// prefetch (T3-minimum 2-phase), global_load_lds staging with pre-swizzled
// global source + XOR-swizzled ds_read (T2, both-sides involution),
// bijective XCD swizzle + fused CurricularFace epilogue + per-(row,nb)
// online (max,sumexp).  grid 3128 x 256
// ---------------------------------------------------------------------------
__global__ __launch_bounds__(256) void k_gemm_fast(
        const unsigned short* __restrict__ xn,    // bf16 [512][512]
        const unsigned short* __restrict__ wnb,   // bf16 [100096][512], normalized
        const int* __restrict__ target,
        const float* __restrict__ ctm,
        const float* __restrict__ ftl,
        const float* __restrict__ tnew,
        float* __restrict__ pmax, float* __restrict__ psum) {
    __shared__ unsigned short As[2][128 * 64];
    __shared__ unsigned short Bs[2][128 * 64];
    __shared__ int   tgt_s[128];
    __shared__ float ctm_s[128];
    __shared__ float ftl_s[128];
    __shared__ float redM[2][128];
    __shared__ float redS[2][128];

    int bx = blockIdx.x;
    int logical = (bx & 7) * WGS_PER_XCD + (bx >> 3);
    int nb = logical >> 2, mb = logical & 3;
    int rowbase = mb * 128, colbase = nb * 128;
    int tid = threadIdx.x;
    int lane = tid & 63, wid = tid >> 6;
    int wm = wid >> 1, wn = wid & 1;

    if (tid < 128) {
        int rg = rowbase + tid;
        tgt_s[tid] = target[rg];
        ctm_s[tid] = ctm[rg];
        ftl_s[tid] = ftl[rg];
    }
    float tn = tnew[0];

    f32x4 acc[4][4];
    #pragma unroll
    for (int m = 0; m < 4; m++)
        #pragma unroll
        for (int n = 0; n < 4; n++)
            acc[m][n] = (f32x4){0.f, 0.f, 0.f, 0.f};

    const char* Ab = (const char*)xn;     // row stride 1024 B
    const char* Bb = (const char*)wnb;    // row stride 1024 B

    // staging: wave wid owns LDS bytes [wid*4096, +4096) of each tile, in 4
    // chunks of 1 KB (64 lanes x 16 B).  LDS dest is linear (wave-uniform
    // base); the T2 swizzle is applied on the per-lane GLOBAL source address
    // (rule #21: involution on source == involution on read).
    #define STAGE(ktv, bufv)                                                      \
        do {                                                                      \
            _Pragma("unroll")                                                     \
            for (int c = 0; c < 4; ++c) {                                         \
                int lo = wid * 4096 + c * 1024;                                   \
                int o  = lo + lane * 16;                                          \
                int row = o >> 7;                                                 \
                int sw  = (o & 127) ^ ((row & 7) << 4);                           \
                GLOAD_LDS16(Ab + (size_t)(rowbase + row) * 1024 + (ktv)*128 + sw, \
                            (char*)As[bufv] + lo);                                \
                GLOAD_LDS16(Bb + (size_t)(colbase + row) * 1024 + (ktv)*128 + sw, \
                            (char*)Bs[bufv] + lo);                                \
            }                                                                     \
        } while (0)

    int fr = lane & 15;
    int kg2 = (lane >> 4) * 16;                   // k-group byte offset
    int swr = (fr & 7) << 4;                       // read-side XOR (row&7 == fr&7)

    STAGE(0, 0);
    __syncthreads();   // drains vmcnt(0): tile 0 staged

    #pragma unroll
    for (int kt = 0; kt < 8; ++kt) {
        int cur = kt & 1;
        if (kt < 7) STAGE(kt + 1, cur ^ 1);       // prefetch overlaps compute
        #pragma unroll
        for (int kk = 0; kk < 2; ++kk) {
            bf16x8 af[4], bfr[4];
            #pragma unroll
            for (int m = 0; m < 4; m++)
                af[m] = *(const bf16x8*)((const char*)As[cur]
                        + (wm*64 + m*16 + fr)*128 + ((kk*64 + kg2) ^ swr));
            #pragma unroll
            for (int n = 0; n < 4; n++)
                bfr[n] = *(const bf16x8*)((const char*)Bs[cur]
                        + (wn*64 + n*16 + fr)*128 + ((kk*64 + kg2) ^ swr));
            #pragma unroll
            for (int m = 0; m < 4; m++)
                #pragma unroll
                for (int n = 0; n < 4; n++)
                    acc[m][n] = __builtin_amdgcn_mfma_f32_16x16x32_bf16(af[m], bfr[n], acc[m][n], 0, 0, 0);
        }
        __syncthreads();   // vmcnt(0) drain (prefetch landed) + buffer handoff
    }
    #undef STAGE

    // ---- fused CurricularFace epilogue + per-row online (max, sumexp) ----
    int cgrp = lane & 15, rgrp = lane >> 4;
    #pragma unroll
    for (int m = 0; m < 4; m++) {
        #pragma unroll
        for (int reg = 0; reg < 4; reg++) {
            int rl = wm * 64 + m * 16 + rgrp * 4 + reg;
            int tr = tgt_s[rl];
            float cm = ctm_s[rl];
            float vv[4];
            bool valid[4];
            #pragma unroll
            for (int n = 0; n < 4; n++) {
                int cl = wn * 64 + n * 16 + cgrp;
                int cgl = colbase + cl;
                float c = acc[m][n][reg];
                c = fminf(fmaxf(c, -1.0f + EPS_F), 1.0f - EPS_F);
                float v;
                if (cgl >= C_CLS)      { v = -3.0e38f; valid[n] = false; }
                else if (cgl == tr)    { v = ftl_s[rl] * SCALE_F; valid[n] = true; }
                else {
                    v = (c > cm) ? c * (tn + c) : c;
                    v *= SCALE_F;
                    valid[n] = true;
                }
                vv[n] = v;
            }
            float mx = fmaxf(fmaxf(vv[0], vv[1]), fmaxf(vv[2], vv[3]));
            #pragma unroll
            for (int msk = 1; msk < 16; msk <<= 1) mx = fmaxf(mx, __shfl_xor(mx, msk));
            float sm = 0.0f;
            #pragma unroll
            for (int n = 0; n < 4; n++) sm += valid[n] ? __expf(vv[n] - mx) : 0.0f;
            #pragma unroll
            for (int msk = 1; msk < 16; msk <<= 1) sm += __shfl_xor(sm, msk);
            if (cgrp == 0) { redM[wn][rl] = mx; redS[wn][rl] = sm; }
        }
    }
    __syncthreads();
    if (tid < 128) {
        float m0 = redM[0][tid], s0 = redS[0][tid];
        float m1 = redM[1][tid], s1 = redS[1][tid];
        float M = fmaxf(m0, m1);
        float S = s0 * __expf(m0 - M) + s1 * __expf(m1 - M);
        size_t idx = (size_t)(rowbase + tid) * NB + nb;
        pmax[idx] = M;
        psum[idx] = S;
    }
}

// ---------------------------------------------------------------------------
// K4 fallback (round-2 version): f32 W load + on-the-fly normalize/convert.
// ---------------------------------------------------------------------------
__global__ __launch_bounds__(256) void k_gemm_epi(
        const unsigned short* __restrict__ xn,
        const float* __restrict__ w,
        const float* __restrict__ wnorm,
        const int* __restrict__ target,
        const float* __restrict__ ctm,
        const float* __restrict__ ftl,
        const float* __restrict__ tnew,
        float* __restrict__ pmax, float* __restrict__ psum) {
    __shared__ unsigned short As[128 * 32];
    __shared__ unsigned short Bs[128 * 32];
    __shared__ int   tgt_s[128];
    __shared__ float ctm_s[128];
    __shared__ float ftl_s[128];
    __shared__ float redM[2][128];
    __shared__ float redS[2][128];

    int bx = blockIdx.x;
    int nb = bx >> 2, mb = bx & 3;
    int rowbase = mb * 128, colbase = nb * 128;
    int tid = threadIdx.x;
    int lane = tid & 63, wid = tid >> 6;
    int wm = wid >> 1, wn = wid & 1;

    if (tid < 128) {
        int rg = rowbase + tid;
        tgt_s[tid] = target[rg];
        ctm_s[tid] = ctm[rg];
        ftl_s[tid] = ftl[rg];
    }
    float tn = tnew[0];

    int srow = tid >> 1;
    int skq  = (tid & 1) * 16;
    int cg = colbase + srow;
    float wscale = 0.0f;
    if (cg < C_CLS) wscale = 1.0f / wnorm[cg];

    f32x4 acc[4][4];
    #pragma unroll
    for (int m = 0; m < 4; m++)
        #pragma unroll
        for (int n = 0; n < 4; n++)
            acc[m][n] = (f32x4){0.f, 0.f, 0.f, 0.f};

    for (int kt = 0; kt < D_DIM / 32; ++kt) {
        int k0 = kt * 32;
        __syncthreads();
        {
            const uint4* src = (const uint4*)(xn + (rowbase + srow) * D_DIM + k0 + skq);
            uint4 a0 = src[0], a1 = src[1];
            *(uint4*)(&As[srow * 32 + skq])     = a0;
            *(uint4*)(&As[srow * 32 + skq + 8]) = a1;
        }
        {
            union { unsigned short h[16]; uint4 q[2]; } pk;
            if (cg < C_CLS) {
                const float4* src = (const float4*)(w + (size_t)cg * D_DIM + k0 + skq);
                #pragma unroll
                for (int q = 0; q < 4; q++) {
                    float4 v = src[q];
                    pk.h[q*4+0] = f2bf(v.x * wscale);
                    pk.h[q*4+1] = f2bf(v.y * wscale);
                    pk.h[q*4+2] = f2bf(v.z * wscale);
                    pk.h[q*4+3] = f2bf(v.w * wscale);
                }
            } else {
                #pragma unroll
                for (int j = 0; j < 16; j++) pk.h[j] = 0;
            }
            *(uint4*)(&Bs[srow * 32 + skq])     = pk.q[0];
            *(uint4*)(&Bs[srow * 32 + skq + 8]) = pk.q[1];
        }
        __syncthreads();
        int fr = lane & 15, kg = (lane >> 4) * 8;
        bf16x8 af[4], bfr[4];
        #pragma unroll
        for (int m = 0; m < 4; m++)
            af[m] = *(const bf16x8*)(&As[(wm * 64 + m * 16 + fr) * 32 + kg]);
        #pragma unroll
        for (int n = 0; n < 4; n++)
            bfr[n] = *(const bf16x8*)(&Bs[(wn * 64 + n * 16 + fr) * 32 + kg]);
        #pragma unroll
        for (int m = 0; m < 4; m++)
            #pragma unroll
            for (int n = 0; n < 4; n++)
                acc[m][n] = __builtin_amdgcn_mfma_f32_16x16x32_bf16(af[m], bfr[n], acc[m][n], 0, 0, 0);
    }

    int cgrp = lane & 15, rgrp = lane >> 4;
    #pragma unroll
    for (int m = 0; m < 4; m++) {
        #pragma unroll
        for (int reg = 0; reg < 4; reg++) {
            int rl = wm * 64 + m * 16 + rgrp * 4 + reg;
            int tr = tgt_s[rl];
            float cm = ctm_s[rl];
            float vv[4];
            bool valid[4];
            #pragma unroll
            for (int n = 0; n < 4; n++) {
                int cl = wn * 64 + n * 16 + cgrp;
                int cgl = colbase + cl;
                float c = acc[m][n][reg];
                c = fminf(fmaxf(c, -1.0f + EPS_F), 1.0f - EPS_F);
                float v;
                if (cgl >= C_CLS)      { v = -3.0e38f; valid[n] = false; }
                else if (cgl == tr)    { v = ftl_s[rl] * SCALE_F; valid[n] = true; }
                else {
                    v = (c > cm) ? c * (tn + c) : c;
                    v *= SCALE_F;
                    valid[n] = true;
                }
                vv[n] = v;
            }
            float mx = fmaxf(fmaxf(vv[0], vv[1]), fmaxf(vv[2], vv[3]));
            #pragma unroll
            for (int msk = 1; msk < 16; msk <<= 1) mx = fmaxf(mx, __shfl_xor(mx, msk));
            float sm = 0.0f;
            #pragma unroll
            for (int n = 0; n < 4; n++) sm += valid[n] ? __expf(vv[n] - mx) : 0.0f;
            #pragma unroll
            for (int msk = 1; msk < 16; msk <<= 1) sm += __shfl_xor(sm, msk);
            if (cgrp == 0) { redM[wn][rl] = mx; redS[wn][rl] = sm; }
        }
    }
    __syncthreads();
    if (tid < 128) {
        float m0 = redM[0][tid], s0 = redS[0][tid];
        float m1 = redM[1][tid], s1 = redS[1][tid];
        float M = fmaxf(m0, m1);
        float S = s0 * __expf(m0 - M) + s1 * __expf(m1 - M);
        size_t idx = (size_t)(rowbase + tid) * NB + nb;
        pmax[idx] = M;
        psum[idx] = S;
    }
}

// K5: per-row logsumexp over NB partials -> loss_i.  grid 512 x 256
__global__ void k_rowlse(const float* __restrict__ pmax, const float* __restrict__ psum,
                         const float* __restrict__ ftl, float* __restrict__ lossi) {
    int row = blockIdx.x, tid = threadIdx.x;
    float M = -3.0e38f, S = 0.0f;
    for (int nb = tid; nb < NB; nb += 256) {
        float m = pmax[(size_t)row * NB + nb];
        float s = psum[(size_t)row * NB + nb];
        float nm = fmaxf(M, m);
        S = S * __expf(M - nm) + s * __expf(m - nm);
        M = nm;
    }
    __shared__ float sM[256], sS[256];
    sM[tid] = M; sS[tid] = S;
    __syncthreads();
    for (int off = 128; off > 0; off >>= 1) {
        if (tid < off) {
            float m2 = sM[tid + off], s2 = sS[tid + off];
            float nm = fmaxf(sM[tid], m2);
            sS[tid] = sS[tid] * __expf(sM[tid] - nm) + s2 * __expf(m2 - nm);
            sM[tid] = nm;
        }
        __syncthreads();
    }
    if (tid == 0) lossi[row] = logf(sS[0]) + sM[0] - SCALE_F * ftl[row];
}

// K6: loss = mean(loss_i).  1 x 512
__global__ void k_final(const float* __restrict__ lossi, float* __restrict__ out) {
    __shared__ float s[512];
    int tid = threadIdx.x;
    s[tid] = lossi[tid];
    __syncthreads();
    for (int off = 256; off > 0; off >>= 1) {
        if (tid < off) s[tid] += s[tid + off];
        __syncthreads();
    }
    if (tid == 0) out[0] = s[0] / 512.0f;
}

extern "C" void kernel_launch(void* const* d_in, const int* in_sizes, int n_in,
                              void* d_out, int out_size, void* d_ws, size_t ws_size,
                              hipStream_t stream) {
    const float* x      = (const float*)d_in[0];
    const float* w      = (const float*)d_in[1];
    const float* t      = (const float*)d_in[2];
    const int*   target = (const int*)d_in[3];

    char* ws = (char*)d_ws;
    unsigned short* xn  = (unsigned short*)(ws + XN_OFF);
    float* xnorm = (float*)(ws + XNORM_OFF);
    float* wnorm = (float*)(ws + WNORM_OFF);
    float* tl    = (float*)(ws + TL_OFF);
    float* ctm   = (float*)(ws + CTM_OFF);
    float* ftl   = (float*)(ws + FTL_OFF);
    float* tnew  = (float*)(ws + TNEW_OFF);
    float* pmax  = (float*)(ws + PMAX_OFF);
    float* psum  = (float*)(ws + PSUM_OFF);
    float* lossi = (float*)(ws + LOSSI_OFF);
    unsigned short* wnb = (unsigned short*)(ws + WNBF_OFF);
    float* out   = (float*)d_out;

    bool fast = (ws_size >= WS_NEED_FAST);

    k_xnorm<<<dim3(N_ROWS), dim3(64), 0, stream>>>(x, xn, xnorm);
    if (fast) {
        k_wnorm_bf16<<<dim3(C_PAD / 4), dim3(256), 0, stream>>>(w, wnorm, wnb);
    } else {
        k_wnorm<<<dim3(C_CLS / 4), dim3(256), 0, stream>>>(w, wnorm);
    }
    k_tlogit<<<dim3(N_ROWS), dim3(64), 0, stream>>>(x, w, xnorm, wnorm, target, tl, ctm, ftl);
    k_tnew<<<dim3(1), dim3(512), 0, stream>>>(tl, t, tnew);
    if (fast) {
        k_gemm_fast<<<dim3(NWG), dim3(256), 0, stream>>>(xn, wnb, target, ctm, ftl, tnew, pmax, psum);
    } else {
        k_gemm_epi<<<dim3(NWG), dim3(256), 0, stream>>>(xn, w, wnorm, target, ctm, ftl, tnew, pmax, psum);
    }
    k_rowlse<<<dim3(N_ROWS), dim3(256), 0, stream>>>(pmax, psum, ftl, lossi);
    k_final<<<dim3(1), dim3(512), 0, stream>>>(lossi, out);
}